// Round 6
// baseline (590.295 us; speedup 1.0000x reference)
//
#include <hip/hip_runtime.h>

#define B_   8
#define D_   256
#define T_   4096
#define NQ_  8
#define K_   1024

#define IDX_OFF  ((size_t)B_ * T_ * D_)             // 8388608
#define LOSS_OFF (IDX_OFF + (size_t)NQ_ * B_ * T_)  // 8650752

// ---- workspace layout (bytes) ----
#define XT_OFF   0ull                      // float xT[32768][256] (32 MB)
#define CB16_OFF 33554432ull               // fp16 codebook in MFMA A-frag order (4 MB)
#define CN_OFF   37748736ull               // float cnorm[8192]
#define LB_OFF   37781504ull               // double lossbuf[8]

typedef _Float16 half8 __attribute__((ext_vector_type(8)));   // 4 VGPR MFMA frag
typedef float   f32x16 __attribute__((ext_vector_type(16)));  // MFMA C/D

__device__ __forceinline__ ushort f2h(float f) {
  return __builtin_bit_cast(ushort, (_Float16)f);
}

// packed score: low 10 mantissa bits replaced by code (single v_and_or_b32)
__device__ __forceinline__ float packsc(float sc, uint code) {
  return __builtin_bit_cast(float, (__builtin_bit_cast(uint, sc) & ~1023u) | code);
}
// sorted top-3 insert via min/max/med3 (4 VALU ops, dep depth 2)
__device__ __forceinline__ void ins3(float& v1, float& v2, float& v3, float f) {
  const float a = v1;
  const float m = fmaxf(v1, f);
  v1 = fminf(v1, f);
  const float v2n = __builtin_amdgcn_fmed3f(a, v2, f);
  v3 = __builtin_amdgcn_fmed3f(v2, v3, m);
  v2 = v2n;
}

// ---- prep 1: x [B,D,T] -> xT f32 [row=b*T+t][d] ----
__global__ void prep_xT(const float* __restrict__ x, float* __restrict__ xT) {
  __shared__ float tile[64][65];
  const int bidx = blockIdx.x;                 // 8 b * 4 dchunk * 64 tchunk
  const int b = bidx >> 8, dc = (bidx >> 6) & 3, tc = bidx & 63;
  const int d0 = dc * 64, t0 = tc * 64;
  const int tid = threadIdx.x;
  {
    const int tt = tid & 63, dg = tid >> 6;
    for (int i = 0; i < 16; ++i) {
      const int d = dg * 16 + i;
      tile[d][tt] = x[((size_t)(b * D_ + d0 + d)) * T_ + t0 + tt];
    }
  }
  __syncthreads();
  {
    const int dw = tid & 63, tg = tid >> 6;
    for (int i = 0; i < 16; ++i) {
      const int t = tg * 16 + i;
      xT[((size_t)b * T_ + t0 + t) * D_ + d0 + dw] = tile[dw][t];
    }
  }
}

// ---- prep 2: cb f32 -> fp16 MFMA A-frag order + f64-accurate cnorm (f32 out) ----
// layout: cb16[stage][tile(code>>5)][ks(k>>4)][lane][8]; lane = ((k>>3)&1)*32 + (code&31), j=k&7
__global__ void prep_cb16(const float* __restrict__ cb, ushort* __restrict__ cb16,
                          float* __restrict__ cnorm) {
  const int tid = threadIdx.x, w = tid >> 6, l = tid & 63;
  const int code = blockIdx.x * 4 + w;         // grid 2048
  const int s = code >> 10, ci = code & 1023, tile = ci >> 5, n = ci & 31;
  const float* row = cb + (size_t)code * D_;
  const float4 v = *(const float4*)(row + l * 4);
  double nrm = (double)v.x * v.x + (double)v.y * v.y + (double)v.z * v.z + (double)v.w * v.w;
  ushort4 p;
  p.x = f2h(v.x); p.y = f2h(v.y); p.z = f2h(v.z); p.w = f2h(v.w);
  const int ks = l >> 2, lf = ((l >> 1) & 1) * 32 + n, j0 = (l & 1) * 4;
  const size_t off = (((size_t)s * 32 + tile) * 16 + ks) * 512 + (size_t)lf * 8 + j0;
  *(ushort4*)(cb16 + off) = p;
#pragma unroll
  for (int m = 1; m <= 32; m <<= 1) nrm += __shfl_xor(nrm, m);
  if (l == 0) cnorm[code] = (float)nrm;
}

// ---- main: 1024 blocks x 256 thr; block = 32 rows; wave w = codes w*256..+255 (8 tiles) ----
// Round-5 falsified the TLP theory (8-wave blocks: dur flat, occ flat) -> the K-loop is
// per-wave LATENCY-bound: chunk-serial A loads expose ~250cy L2 latency per 32cy of MFMA.
// This version adds ILP instead:
//   * flattened 32-chunk K-loop, rotating pa[i%3] A-prefetch (static idx under full unroll):
//     chunk i+2's loads issue before chunk i's MFMAs -> ~2 chunks in flight per wave.
//   * B fragments register-resident per stage (16 ds_read_b128 once; tile-invariant).
//     NO waves_per_eu attribute: natural allocation (round 4 showed no-clamp => no spill).
//   * cnorm prefetched at tile start (hides its once-per-tile latency).
__global__ __launch_bounds__(256)
void rvq_main(const float* __restrict__ cb, const float* __restrict__ xT,
              const ushort* __restrict__ cb16, const float* __restrict__ cnorm,
              float* __restrict__ out, double* __restrict__ lossbuf) {
  __shared__ __align__(16) uint4  res16[1024];      // 16 KB fp16 residual, B-frag layout
  __shared__ float candm[32][12];                   // packed score|code, 1.5 KB

  const int tid = threadIdx.x;
  const int w = tid >> 6, l = tid & 63, n5 = l & 31, h = l >> 5;
  const size_t row0 = (size_t)blockIdx.x * 32;
  const int rowL = tid >> 3;            // phase-3 row  (== w*8 + (l>>3))
  const int dq = tid & 7;               // phase-3 dim-octant (32 dims)

  float res[4][8];                      // f32 residual (reference arithmetic), register-resident

  // ---- init: residual = x; write fp16 frag image ----
  {
#pragma unroll
    for (int cc = 0; cc < 4; ++cc) {
      const int kb = dq * 4 + cc;
      const float* xp = xT + (row0 + rowL) * D_ + kb * 8;
      const float4 x0 = *(const float4*)xp, x1 = *(const float4*)(xp + 4);
      res[cc][0] = x0.x; res[cc][1] = x0.y; res[cc][2] = x0.z; res[cc][3] = x0.w;
      res[cc][4] = x1.x; res[cc][5] = x1.y; res[cc][6] = x1.z; res[cc][7] = x1.w;
      uint4 pv;
      pv.x = __builtin_bit_cast(uint, __builtin_amdgcn_cvt_pkrtz(x0.x, x0.y));
      pv.y = __builtin_bit_cast(uint, __builtin_amdgcn_cvt_pkrtz(x0.z, x0.w));
      pv.z = __builtin_bit_cast(uint, __builtin_amdgcn_cvt_pkrtz(x1.x, x1.y));
      pv.w = __builtin_bit_cast(uint, __builtin_amdgcn_cvt_pkrtz(x1.z, x1.w));
      res16[kb * 32 + (rowL ^ dq)] = pv;           // (kb>>2)&7 == dq
    }
  }
  __syncthreads();

  for (int s = 0; s < NQ_; ++s) {
    // ===== prologue: A chunks 0,1 in flight, then B fragments (16 ds_read_b128) =====
    const uint4* ap0 = (const uint4*)(cb16 + ((size_t)(s * 32 + w * 8) * 16) * 512) + l;
    uint4 pa[3][4];
#pragma unroll
    for (int c = 0; c < 4; ++c) pa[0][c] = ap0[c * 64];
#pragma unroll
    for (int c = 0; c < 4; ++c) pa[1][c] = ap0[(4 + c) * 64];
    half8 b[16];
#pragma unroll
    for (int ks = 0; ks < 16; ++ks) {
      const uint4 bv = res16[(ks * 2 + h) * 32 + (n5 ^ ((ks >> 1) & 7))];
      b[ks] = __builtin_bit_cast(half8, bv);
    }

    // ===== K-loop: flattened 32 chunks (8 tiles x 4), rotating 3-slot A prefetch =====
    float v1 = 3e38f, v2 = 3e38f, v3 = 3e38f;   // chain A
    float u1 = 3e38f, u2 = 3e38f, u3 = 3e38f;   // chain B
    f32x16 acc;
    float4 cq[4];
#pragma unroll
    for (int i = 0; i < 32; ++i) {
      const int tt = i >> 2, q = i & 3;
      if (q == 0) {
        const float* cnb = cnorm + s * K_ + (w * 8 + tt) * 32 + h * 4;
        cq[0] = *(const float4*)(cnb);
        cq[1] = *(const float4*)(cnb + 8);
        cq[2] = *(const float4*)(cnb + 16);
        cq[3] = *(const float4*)(cnb + 24);
#pragma unroll
        for (int r = 0; r < 16; ++r) acc[r] = 0.0f;
      }
      if (i + 2 < 32) {                          // issue chunk i+2 before consuming chunk i
        const int i2 = i + 2, t2 = i2 >> 2, q2 = i2 & 3, s2 = i2 % 3;
#pragma unroll
        for (int c = 0; c < 4; ++c) pa[s2][c] = ap0[t2 * 1024 + (q2 * 4 + c) * 64];
      }
      const int sl = i % 3;
#pragma unroll
      for (int c = 0; c < 4; ++c) {
        acc = __builtin_amdgcn_mfma_f32_32x32x16_f16(
            __builtin_bit_cast(half8, pa[sl][c]), b[q * 4 + c], acc, 0, 0, 0);
      }
      if (q == 3) {
        const uint cbase = (uint)((w * 8 + tt) * 32 + 4 * h);
#pragma unroll
        for (int qq = 0; qq < 4; ++qq) {
          const float cna[4] = {cq[qq].x, cq[qq].y, cq[qq].z, cq[qq].w};
#pragma unroll
          for (int rr = 0; rr < 4; ++rr) {
            const float sc = fmaf(-2.0f, acc[qq * 4 + rr], cna[rr]);
            const uint code = cbase + (uint)(8 * qq + rr);  // == t*32 + (r&3) + 8*(r>>2) + 4*h
            const float f = packsc(sc, code);
            if (rr & 1) ins3(u1, u2, u3, f);
            else        ins3(v1, v2, v3, f);
          }
        }
      }
    }
    // merge chain B into chain A
    ins3(v1, v2, v3, u1);
    ins3(v1, v2, v3, u2);
    ins3(v1, v2, v3, u3);
    // merge h-halves (lane l <-> l^32, same x-row, disjoint codes)
    {
      const float o1 = __shfl_xor(v1, 32), o2 = __shfl_xor(v2, 32), o3 = __shfl_xor(v3, 32);
      ins3(v1, v2, v3, o1);
      ins3(v1, v2, v3, o2);
      ins3(v1, v2, v3, o3);
    }
    if (h == 0) {
      candm[n5][w * 3 + 0] = v1;
      candm[n5][w * 3 + 1] = v2;
      candm[n5][w * 3 + 2] = v3;
    }
    __syncthreads();   // all K-loop res16 reads done before phase-3 rewrites

    // ===== phase 3: 8 lanes/row x 32 dims; f64 re-eval of top-3-of-12 (f32 residual) =====
    double lossW = 0.0;
    {
      float m1 = 3e38f, m2 = 3e38f, m3 = 3e38f;
#pragma unroll
      for (int cd = 0; cd < 12; ++cd) ins3(m1, m2, m3, candm[rowL][cd]);
      const int c1 = (int)(__builtin_bit_cast(uint, m1) & 1023u);
      const int c2 = (int)(__builtin_bit_cast(uint, m2) & 1023u);
      const int c3 = (int)(__builtin_bit_cast(uint, m3) & 1023u);

      const float* cbs = cb + (size_t)s * K_ * D_;
      const float* cr0 = cbs + (size_t)c1 * D_;
      const float* cr1 = cbs + (size_t)c2 * D_;
      const float* cr2 = cbs + (size_t)c3 * D_;
      double dd0 = 0.0, dd1 = 0.0, dd2 = 0.0;
#pragma unroll
      for (int cc = 0; cc < 4; ++cc) {
        const int kb = dq * 4 + cc;
        const int go = kb * 8;
        const float4 a0 = *(const float4*)(cr0 + go), a1 = *(const float4*)(cr0 + go + 4);
        const float4 b0 = *(const float4*)(cr1 + go), b1 = *(const float4*)(cr1 + go + 4);
        const float4 g0 = *(const float4*)(cr2 + go), g1 = *(const float4*)(cr2 + go + 4);
        const float af[8] = {a0.x, a0.y, a0.z, a0.w, a1.x, a1.y, a1.z, a1.w};
        const float bf[8] = {b0.x, b0.y, b0.z, b0.w, b1.x, b1.y, b1.z, b1.w};
        const float gf[8] = {g0.x, g0.y, g0.z, g0.w, g1.x, g1.y, g1.z, g1.w};
#pragma unroll
        for (int j = 0; j < 8; ++j) {
          const double r64 = (double)res[cc][j];
          const double u = r64 - (double)af[j]; dd0 += u * u;
          const double v = r64 - (double)bf[j]; dd1 += v * v;
          const double gg = r64 - (double)gf[j]; dd2 += gg * gg;
        }
      }
#pragma unroll
      for (int m = 1; m <= 4; m <<= 1) {
        dd0 += __shfl_xor(dd0, m); dd1 += __shfl_xor(dd1, m); dd2 += __shfl_xor(dd2, m);
      }
      int win = c1; double dwn = dd0;
      if (dd1 < dwn || (dd1 == dwn && c2 < win)) { win = c2; dwn = dd1; }
      if (dd2 < dwn || (dd2 == dwn && c3 < win)) { win = c3; dwn = dd2; }
      const float* crw = cbs + (size_t)win * D_;
#pragma unroll
      for (int cc = 0; cc < 4; ++cc) {
        const int kb = dq * 4 + cc;
        const int go = kb * 8;
        const float4 w0 = *(const float4*)(crw + go), w1 = *(const float4*)(crw + go + 4);
        const float wf[8] = {w0.x, w0.y, w0.z, w0.w, w1.x, w1.y, w1.z, w1.w};
        if (s < NQ_ - 1) {
#pragma unroll
          for (int j = 0; j < 8; ++j) res[cc][j] = res[cc][j] - wf[j];   // f32: matches reference
          uint4 pv;
          pv.x = __builtin_bit_cast(uint, __builtin_amdgcn_cvt_pkrtz(res[cc][0], res[cc][1]));
          pv.y = __builtin_bit_cast(uint, __builtin_amdgcn_cvt_pkrtz(res[cc][2], res[cc][3]));
          pv.z = __builtin_bit_cast(uint, __builtin_amdgcn_cvt_pkrtz(res[cc][4], res[cc][5]));
          pv.w = __builtin_bit_cast(uint, __builtin_amdgcn_cvt_pkrtz(res[cc][6], res[cc][7]));
          res16[kb * 32 + (rowL ^ dq)] = pv;
        } else {
          const float* xp = xT + (row0 + rowL) * D_ + go;
          const float4 x0 = *(const float4*)xp, x1 = *(const float4*)(xp + 4);
          const float xf[8] = {x0.x, x0.y, x0.z, x0.w, x1.x, x1.y, x1.z, x1.w};
          float o[8];
#pragma unroll
          for (int j = 0; j < 8; ++j) o[j] = xf[j] - (res[cc][j] - wf[j]);
          float* od = out + (row0 + rowL) * D_ + go;
          *(float4*)od       = make_float4(o[0], o[1], o[2], o[3]);
          *(float4*)(od + 4) = make_float4(o[4], o[5], o[6], o[7]);
        }
      }
      if (dq == 0) {
        out[IDX_OFF + (size_t)s * (B_ * T_) + row0 + rowL] = (float)win;
        lossW = dwn;
      }
    }
    // lossW nonzero only on lanes with dq==0 (l % 8 == 0): masks 8/16/32 suffice
#pragma unroll
    for (int m = 8; m <= 32; m <<= 1) lossW += __shfl_xor(lossW, m);
    if (l == 0) atomicAdd(&lossbuf[s], lossW);
    __syncthreads();
  }
}

__global__ void rvq_loss(const double* __restrict__ lossbuf, float* __restrict__ out) {
  const int s = threadIdx.x;
  if (s < NQ_) out[LOSS_OFF + s] = (float)(2.0 * lossbuf[s] / (double)((size_t)B_ * T_ * D_));
}

extern "C" void kernel_launch(void* const* d_in, const int* in_sizes, int n_in,
                              void* d_out, int out_size, void* d_ws, size_t ws_size,
                              hipStream_t stream) {
  const float* x  = (const float*)d_in[0];   // [B, D, T] f32
  const float* cb = (const float*)d_in[1];   // [NQ, K, D] f32
  float* out = (float*)d_out;
  char* ws = (char*)d_ws;
  float*  xTp   = (float*)(ws + XT_OFF);
  ushort* cb16p = (ushort*)(ws + CB16_OFF);
  float*  cnp   = (float*)(ws + CN_OFF);
  double* lbp   = (double*)(ws + LB_OFF);

  hipMemsetAsync(ws + LB_OFF, 0, NQ_ * sizeof(double), stream);
  prep_xT<<<2048, 256, 0, stream>>>(x, xTp);
  prep_cb16<<<2048, 256, 0, stream>>>(cb, cb16p, cnp);
  rvq_main<<<1024, 256, 0, stream>>>(cb, xTp, cb16p, cnp, out, lbp);
  rvq_loss<<<1, 64, 0, stream>>>(lbp, out);
}

// Round 7
// 553.224 us; speedup vs baseline: 1.0670x; 1.0670x over previous
//
#include <hip/hip_runtime.h>

#define B_   8
#define D_   256
#define T_   4096
#define NQ_  8
#define K_   1024

#define IDX_OFF  ((size_t)B_ * T_ * D_)             // 8388608
#define LOSS_OFF (IDX_OFF + (size_t)NQ_ * B_ * T_)  // 8650752

// ---- workspace layout (bytes) ----
#define XT_OFF   0ull                      // float xT[32768][256] (32 MB)
#define CB16_OFF 33554432ull               // fp16 codebook in MFMA A-frag order (4 MB)
#define CN_OFF   37748736ull               // float cnorm[8192]
#define LB_OFF   37781504ull               // double lossbuf[8][1024] (64 KB, per-block slots)

typedef _Float16 half8 __attribute__((ext_vector_type(8)));   // 4 VGPR MFMA frag
typedef float   f32x16 __attribute__((ext_vector_type(16)));  // MFMA C/D

__device__ __forceinline__ ushort f2h(float f) {
  return __builtin_bit_cast(ushort, (_Float16)f);
}

// packed score: low 10 mantissa bits replaced by code (single v_and_or_b32)
__device__ __forceinline__ float packsc(float sc, uint code) {
  return __builtin_bit_cast(float, (__builtin_bit_cast(uint, sc) & ~1023u) | code);
}
// sorted top-3 insert via min/max/med3 (4 VALU ops, dep depth 2)
__device__ __forceinline__ void ins3(float& v1, float& v2, float& v3, float f) {
  const float a = v1;
  const float m = fmaxf(v1, f);
  v1 = fminf(v1, f);
  const float v2n = __builtin_amdgcn_fmed3f(a, v2, f);
  v3 = __builtin_amdgcn_fmed3f(v2, v3, m);
  v2 = v2n;
}

// ---- prep 1: x [B,D,T] -> xT f32 [row=b*T+t][d] ----
__global__ void prep_xT(const float* __restrict__ x, float* __restrict__ xT) {
  __shared__ float tile[64][65];
  const int bidx = blockIdx.x;                 // 8 b * 4 dchunk * 64 tchunk
  const int b = bidx >> 8, dc = (bidx >> 6) & 3, tc = bidx & 63;
  const int d0 = dc * 64, t0 = tc * 64;
  const int tid = threadIdx.x;
  {
    const int tt = tid & 63, dg = tid >> 6;
    for (int i = 0; i < 16; ++i) {
      const int d = dg * 16 + i;
      tile[d][tt] = x[((size_t)(b * D_ + d0 + d)) * T_ + t0 + tt];
    }
  }
  __syncthreads();
  {
    const int dw = tid & 63, tg = tid >> 6;
    for (int i = 0; i < 16; ++i) {
      const int t = tg * 16 + i;
      xT[((size_t)b * T_ + t0 + t) * D_ + d0 + dw] = tile[dw][t];
    }
  }
}

// ---- prep 2: cb f32 -> fp16 MFMA A-frag order + f64-accurate cnorm (f32 out) ----
// layout: cb16[stage][tile(code>>5)][ks(k>>4)][lane][8]; lane = ((k>>3)&1)*32 + (code&31), j=k&7
__global__ void prep_cb16(const float* __restrict__ cb, ushort* __restrict__ cb16,
                          float* __restrict__ cnorm) {
  const int tid = threadIdx.x, w = tid >> 6, l = tid & 63;
  const int code = blockIdx.x * 4 + w;         // grid 2048
  const int s = code >> 10, ci = code & 1023, tile = ci >> 5, n = ci & 31;
  const float* row = cb + (size_t)code * D_;
  const float4 v = *(const float4*)(row + l * 4);
  double nrm = (double)v.x * v.x + (double)v.y * v.y + (double)v.z * v.z + (double)v.w * v.w;
  ushort4 p;
  p.x = f2h(v.x); p.y = f2h(v.y); p.z = f2h(v.z); p.w = f2h(v.w);
  const int ks = l >> 2, lf = ((l >> 1) & 1) * 32 + n, j0 = (l & 1) * 4;
  const size_t off = (((size_t)s * 32 + tile) * 16 + ks) * 512 + (size_t)lf * 8 + j0;
  *(ushort4*)(cb16 + off) = p;
#pragma unroll
  for (int m = 1; m <= 32; m <<= 1) nrm += __shfl_xor(nrm, m);
  if (l == 0) cnorm[code] = (float)nrm;
}

// ---- main: 1024 blocks x 256 thr; block = 32 rows; wave w = codes w*256..+255 (8 tiles) ----
// ROUND-7 CHANGE (single variable): the per-stage loss atomicAdd on ONE double was a
// device-wide serializer: 4096 same-address f64 atomics/stage, each wave forced to wait
// for its atomic at the stage-boundary __syncthreads (vmcnt(0) drain) -> ~123K cy/stage
// of serialized L2 atomic service ~= the entire 515-530us plateau, invariant to all
// occupancy/ILP changes (rounds 0-6). Now: block-level LDS reduce + plain store to a
// per-block slot lossbuf[s][bid]; separate 8-block reduction kernel sums them.
// K-loop/phase-3 structure identical to round 6 (passing).
__global__ __launch_bounds__(256)
void rvq_main(const float* __restrict__ cb, const float* __restrict__ xT,
              const ushort* __restrict__ cb16, const float* __restrict__ cnorm,
              float* __restrict__ out, double* __restrict__ lossbuf) {
  __shared__ __align__(16) uint4  res16[1024];      // 16 KB fp16 residual, B-frag layout
  __shared__ float candm[32][12];                   // packed score|code, 1.5 KB
  __shared__ double lred[4];                        // per-wave loss partials

  const int tid = threadIdx.x;
  const int w = tid >> 6, l = tid & 63, n5 = l & 31, h = l >> 5;
  const size_t row0 = (size_t)blockIdx.x * 32;
  const int rowL = tid >> 3;            // phase-3 row  (== w*8 + (l>>3))
  const int dq = tid & 7;               // phase-3 dim-octant (32 dims)

  float res[4][8];                      // f32 residual (reference arithmetic), register-resident

  // ---- init: residual = x; write fp16 frag image ----
  {
#pragma unroll
    for (int cc = 0; cc < 4; ++cc) {
      const int kb = dq * 4 + cc;
      const float* xp = xT + (row0 + rowL) * D_ + kb * 8;
      const float4 x0 = *(const float4*)xp, x1 = *(const float4*)(xp + 4);
      res[cc][0] = x0.x; res[cc][1] = x0.y; res[cc][2] = x0.z; res[cc][3] = x0.w;
      res[cc][4] = x1.x; res[cc][5] = x1.y; res[cc][6] = x1.z; res[cc][7] = x1.w;
      uint4 pv;
      pv.x = __builtin_bit_cast(uint, __builtin_amdgcn_cvt_pkrtz(x0.x, x0.y));
      pv.y = __builtin_bit_cast(uint, __builtin_amdgcn_cvt_pkrtz(x0.z, x0.w));
      pv.z = __builtin_bit_cast(uint, __builtin_amdgcn_cvt_pkrtz(x1.x, x1.y));
      pv.w = __builtin_bit_cast(uint, __builtin_amdgcn_cvt_pkrtz(x1.z, x1.w));
      res16[kb * 32 + (rowL ^ dq)] = pv;           // (kb>>2)&7 == dq
    }
  }
  __syncthreads();

  for (int s = 0; s < NQ_; ++s) {
    // ===== prologue: A chunks 0,1 in flight, then B fragments (16 ds_read_b128) =====
    const uint4* ap0 = (const uint4*)(cb16 + ((size_t)(s * 32 + w * 8) * 16) * 512) + l;
    uint4 pa[3][4];
#pragma unroll
    for (int c = 0; c < 4; ++c) pa[0][c] = ap0[c * 64];
#pragma unroll
    for (int c = 0; c < 4; ++c) pa[1][c] = ap0[(4 + c) * 64];
    half8 b[16];
#pragma unroll
    for (int ks = 0; ks < 16; ++ks) {
      const uint4 bv = res16[(ks * 2 + h) * 32 + (n5 ^ ((ks >> 1) & 7))];
      b[ks] = __builtin_bit_cast(half8, bv);
    }

    // ===== K-loop: flattened 32 chunks (8 tiles x 4), rotating 3-slot A prefetch =====
    float v1 = 3e38f, v2 = 3e38f, v3 = 3e38f;   // chain A
    float u1 = 3e38f, u2 = 3e38f, u3 = 3e38f;   // chain B
    f32x16 acc;
    float4 cq[4];
#pragma unroll
    for (int i = 0; i < 32; ++i) {
      const int tt = i >> 2, q = i & 3;
      if (q == 0) {
        const float* cnb = cnorm + s * K_ + (w * 8 + tt) * 32 + h * 4;
        cq[0] = *(const float4*)(cnb);
        cq[1] = *(const float4*)(cnb + 8);
        cq[2] = *(const float4*)(cnb + 16);
        cq[3] = *(const float4*)(cnb + 24);
#pragma unroll
        for (int r = 0; r < 16; ++r) acc[r] = 0.0f;
      }
      if (i + 2 < 32) {                          // issue chunk i+2 before consuming chunk i
        const int i2 = i + 2, t2 = i2 >> 2, q2 = i2 & 3, s2 = i2 % 3;
#pragma unroll
        for (int c = 0; c < 4; ++c) pa[s2][c] = ap0[t2 * 1024 + (q2 * 4 + c) * 64];
      }
      const int sl = i % 3;
#pragma unroll
      for (int c = 0; c < 4; ++c) {
        acc = __builtin_amdgcn_mfma_f32_32x32x16_f16(
            __builtin_bit_cast(half8, pa[sl][c]), b[q * 4 + c], acc, 0, 0, 0);
      }
      if (q == 3) {
        const uint cbase = (uint)((w * 8 + tt) * 32 + 4 * h);
#pragma unroll
        for (int qq = 0; qq < 4; ++qq) {
          const float cna[4] = {cq[qq].x, cq[qq].y, cq[qq].z, cq[qq].w};
#pragma unroll
          for (int rr = 0; rr < 4; ++rr) {
            const float sc = fmaf(-2.0f, acc[qq * 4 + rr], cna[rr]);
            const uint code = cbase + (uint)(8 * qq + rr);  // == t*32 + (r&3) + 8*(r>>2) + 4*h
            const float f = packsc(sc, code);
            if (rr & 1) ins3(u1, u2, u3, f);
            else        ins3(v1, v2, v3, f);
          }
        }
      }
    }
    // merge chain B into chain A
    ins3(v1, v2, v3, u1);
    ins3(v1, v2, v3, u2);
    ins3(v1, v2, v3, u3);
    // merge h-halves (lane l <-> l^32, same x-row, disjoint codes)
    {
      const float o1 = __shfl_xor(v1, 32), o2 = __shfl_xor(v2, 32), o3 = __shfl_xor(v3, 32);
      ins3(v1, v2, v3, o1);
      ins3(v1, v2, v3, o2);
      ins3(v1, v2, v3, o3);
    }
    if (h == 0) {
      candm[n5][w * 3 + 0] = v1;
      candm[n5][w * 3 + 1] = v2;
      candm[n5][w * 3 + 2] = v3;
    }
    __syncthreads();   // all K-loop res16 reads done before phase-3 rewrites

    // ===== phase 3: 8 lanes/row x 32 dims; f64 re-eval of top-3-of-12 (f32 residual) =====
    double lossW = 0.0;
    {
      float m1 = 3e38f, m2 = 3e38f, m3 = 3e38f;
#pragma unroll
      for (int cd = 0; cd < 12; ++cd) ins3(m1, m2, m3, candm[rowL][cd]);
      const int c1 = (int)(__builtin_bit_cast(uint, m1) & 1023u);
      const int c2 = (int)(__builtin_bit_cast(uint, m2) & 1023u);
      const int c3 = (int)(__builtin_bit_cast(uint, m3) & 1023u);

      const float* cbs = cb + (size_t)s * K_ * D_;
      const float* cr0 = cbs + (size_t)c1 * D_;
      const float* cr1 = cbs + (size_t)c2 * D_;
      const float* cr2 = cbs + (size_t)c3 * D_;
      double dd0 = 0.0, dd1 = 0.0, dd2 = 0.0;
#pragma unroll
      for (int cc = 0; cc < 4; ++cc) {
        const int kb = dq * 4 + cc;
        const int go = kb * 8;
        const float4 a0 = *(const float4*)(cr0 + go), a1 = *(const float4*)(cr0 + go + 4);
        const float4 b0 = *(const float4*)(cr1 + go), b1 = *(const float4*)(cr1 + go + 4);
        const float4 g0 = *(const float4*)(cr2 + go), g1 = *(const float4*)(cr2 + go + 4);
        const float af[8] = {a0.x, a0.y, a0.z, a0.w, a1.x, a1.y, a1.z, a1.w};
        const float bf[8] = {b0.x, b0.y, b0.z, b0.w, b1.x, b1.y, b1.z, b1.w};
        const float gf[8] = {g0.x, g0.y, g0.z, g0.w, g1.x, g1.y, g1.z, g1.w};
#pragma unroll
        for (int j = 0; j < 8; ++j) {
          const double r64 = (double)res[cc][j];
          const double u = r64 - (double)af[j]; dd0 += u * u;
          const double v = r64 - (double)bf[j]; dd1 += v * v;
          const double gg = r64 - (double)gf[j]; dd2 += gg * gg;
        }
      }
#pragma unroll
      for (int m = 1; m <= 4; m <<= 1) {
        dd0 += __shfl_xor(dd0, m); dd1 += __shfl_xor(dd1, m); dd2 += __shfl_xor(dd2, m);
      }
      int win = c1; double dwn = dd0;
      if (dd1 < dwn || (dd1 == dwn && c2 < win)) { win = c2; dwn = dd1; }
      if (dd2 < dwn || (dd2 == dwn && c3 < win)) { win = c3; dwn = dd2; }
      const float* crw = cbs + (size_t)win * D_;
#pragma unroll
      for (int cc = 0; cc < 4; ++cc) {
        const int kb = dq * 4 + cc;
        const int go = kb * 8;
        const float4 w0 = *(const float4*)(crw + go), w1 = *(const float4*)(crw + go + 4);
        const float wf[8] = {w0.x, w0.y, w0.z, w0.w, w1.x, w1.y, w1.z, w1.w};
        if (s < NQ_ - 1) {
#pragma unroll
          for (int j = 0; j < 8; ++j) res[cc][j] = res[cc][j] - wf[j];   // f32: matches reference
          uint4 pv;
          pv.x = __builtin_bit_cast(uint, __builtin_amdgcn_cvt_pkrtz(res[cc][0], res[cc][1]));
          pv.y = __builtin_bit_cast(uint, __builtin_amdgcn_cvt_pkrtz(res[cc][2], res[cc][3]));
          pv.z = __builtin_bit_cast(uint, __builtin_amdgcn_cvt_pkrtz(res[cc][4], res[cc][5]));
          pv.w = __builtin_bit_cast(uint, __builtin_amdgcn_cvt_pkrtz(res[cc][6], res[cc][7]));
          res16[kb * 32 + (rowL ^ dq)] = pv;
        } else {
          const float* xp = xT + (row0 + rowL) * D_ + go;
          const float4 x0 = *(const float4*)xp, x1 = *(const float4*)(xp + 4);
          const float xf[8] = {x0.x, x0.y, x0.z, x0.w, x1.x, x1.y, x1.z, x1.w};
          float o[8];
#pragma unroll
          for (int j = 0; j < 8; ++j) o[j] = xf[j] - (res[cc][j] - wf[j]);
          float* od = out + (row0 + rowL) * D_ + go;
          *(float4*)od       = make_float4(o[0], o[1], o[2], o[3]);
          *(float4*)(od + 4) = make_float4(o[4], o[5], o[6], o[7]);
        }
      }
      if (dq == 0) {
        out[IDX_OFF + (size_t)s * (B_ * T_) + row0 + rowL] = (float)win;
        lossW = dwn;
      }
    }
    // lossW nonzero only on lanes with dq==0 (l % 8 == 0): masks 8/16/32 suffice
#pragma unroll
    for (int m = 8; m <= 32; m <<= 1) lossW += __shfl_xor(lossW, m);
    if (l == 0) lred[w] = lossW;          // per-wave partial -> LDS (no atomics!)
    __syncthreads();
    if (tid == 0)                         // one plain store per block per stage, own slot
      lossbuf[(size_t)s * 1024 + blockIdx.x] = lred[0] + lred[1] + lred[2] + lred[3];
  }
}

// ---- loss reduce: 8 blocks x 256 thr; block s sums its 1024 per-block partials ----
__global__ void rvq_loss(const double* __restrict__ lossbuf, float* __restrict__ out) {
  const int s = blockIdx.x, tid = threadIdx.x;
  double acc = 0.0;
#pragma unroll
  for (int i = 0; i < 4; ++i) acc += lossbuf[(size_t)s * 1024 + tid + i * 256];
#pragma unroll
  for (int m = 1; m <= 32; m <<= 1) acc += __shfl_xor(acc, m);
  __shared__ double sred[4];
  if ((tid & 63) == 0) sred[tid >> 6] = acc;
  __syncthreads();
  if (tid == 0)
    out[LOSS_OFF + s] =
        (float)(2.0 * (sred[0] + sred[1] + sred[2] + sred[3]) / (double)((size_t)B_ * T_ * D_));
}

extern "C" void kernel_launch(void* const* d_in, const int* in_sizes, int n_in,
                              void* d_out, int out_size, void* d_ws, size_t ws_size,
                              hipStream_t stream) {
  const float* x  = (const float*)d_in[0];   // [B, D, T] f32
  const float* cb = (const float*)d_in[1];   // [NQ, K, D] f32
  float* out = (float*)d_out;
  char* ws = (char*)d_ws;
  float*  xTp   = (float*)(ws + XT_OFF);
  ushort* cb16p = (ushort*)(ws + CB16_OFF);
  float*  cnp   = (float*)(ws + CN_OFF);
  double* lbp   = (double*)(ws + LB_OFF);

  prep_xT<<<2048, 256, 0, stream>>>(x, xTp);
  prep_cb16<<<2048, 256, 0, stream>>>(cb, cb16p, cnp);
  rvq_main<<<1024, 256, 0, stream>>>(cb, xTp, cb16p, cnp, out, lbp);
  rvq_loss<<<8, 256, 0, stream>>>(lbp, out);
}

// Round 8
// 490.332 us; speedup vs baseline: 1.2039x; 1.1283x over previous
//
#include <hip/hip_runtime.h>

#define B_   8
#define D_   256
#define T_   4096
#define NQ_  8
#define K_   1024

#define IDX_OFF  ((size_t)B_ * T_ * D_)             // 8388608
#define LOSS_OFF (IDX_OFF + (size_t)NQ_ * B_ * T_)  // 8650752

// ---- workspace layout (bytes) ----
#define XT_OFF   0ull                      // float xT[32768][256] (32 MB)
#define CB16_OFF 33554432ull               // fp16 codebook in MFMA A-frag order (4 MB)
#define CN_OFF   37748736ull               // float cnorm[8192]
#define LB_OFF   37781504ull               // double lossbuf[8][512] (32 KB, per-block slots)

typedef _Float16 half8 __attribute__((ext_vector_type(8)));   // 4 VGPR MFMA frag
typedef float   f32x16 __attribute__((ext_vector_type(16)));  // MFMA C/D

__device__ __forceinline__ ushort f2h(float f) {
  return __builtin_bit_cast(ushort, (_Float16)f);
}

// packed score: low 10 mantissa bits replaced by code (single v_and_or_b32)
__device__ __forceinline__ float packsc(float sc, uint code) {
  return __builtin_bit_cast(float, (__builtin_bit_cast(uint, sc) & ~1023u) | code);
}
// sorted top-3 insert via min/max/med3 (4 VALU ops, dep depth 2)
__device__ __forceinline__ void ins3(float& v1, float& v2, float& v3, float f) {
  const float a = v1;
  const float m = fmaxf(v1, f);
  v1 = fminf(v1, f);
  const float v2n = __builtin_amdgcn_fmed3f(a, v2, f);
  v3 = __builtin_amdgcn_fmed3f(v2, v3, m);
  v2 = v2n;
}

// ---- prep 1: x [B,D,T] -> xT f32 [row=b*T+t][d] ----
__global__ void prep_xT(const float* __restrict__ x, float* __restrict__ xT) {
  __shared__ float tile[64][65];
  const int bidx = blockIdx.x;                 // 8 b * 4 dchunk * 64 tchunk
  const int b = bidx >> 8, dc = (bidx >> 6) & 3, tc = bidx & 63;
  const int d0 = dc * 64, t0 = tc * 64;
  const int tid = threadIdx.x;
  {
    const int tt = tid & 63, dg = tid >> 6;
    for (int i = 0; i < 16; ++i) {
      const int d = dg * 16 + i;
      tile[d][tt] = x[((size_t)(b * D_ + d0 + d)) * T_ + t0 + tt];
    }
  }
  __syncthreads();
  {
    const int dw = tid & 63, tg = tid >> 6;
    for (int i = 0; i < 16; ++i) {
      const int t = tg * 16 + i;
      xT[((size_t)b * T_ + t0 + t) * D_ + d0 + dw] = tile[dw][t];
    }
  }
}

// ---- prep 2: cb f32 -> fp16 MFMA A-frag order + f64-accurate cnorm (f32 out) ----
// layout: cb16[stage][tile(code>>5)][ks(k>>4)][lane][8]; lane = ((k>>3)&1)*32 + (code&31), j=k&7
__global__ void prep_cb16(const float* __restrict__ cb, ushort* __restrict__ cb16,
                          float* __restrict__ cnorm) {
  const int tid = threadIdx.x, w = tid >> 6, l = tid & 63;
  const int code = blockIdx.x * 4 + w;         // grid 2048
  const int s = code >> 10, ci = code & 1023, tile = ci >> 5, n = ci & 31;
  const float* row = cb + (size_t)code * D_;
  const float4 v = *(const float4*)(row + l * 4);
  double nrm = (double)v.x * v.x + (double)v.y * v.y + (double)v.z * v.z + (double)v.w * v.w;
  ushort4 p;
  p.x = f2h(v.x); p.y = f2h(v.y); p.z = f2h(v.z); p.w = f2h(v.w);
  const int ks = l >> 2, lf = ((l >> 1) & 1) * 32 + n, j0 = (l & 1) * 4;
  const size_t off = (((size_t)s * 32 + tile) * 16 + ks) * 512 + (size_t)lf * 8 + j0;
  *(ushort4*)(cb16 + off) = p;
#pragma unroll
  for (int m = 1; m <= 32; m <<= 1) nrm += __shfl_xor(nrm, m);
  if (l == 0) cnorm[code] = (float)nrm;
}

// ---- main: 512 blocks x 256 thr; block = 64 rows (2 row-groups); wave w = codes w*256..+255 ----
// ROUND-8 THEORY: the invariant across rounds 0-7 was the per-CU A-load stream: every block
// read the full 512KB stage codebook -> 1024 blk x 4MB = 16 MB/CU through the L1/TA path at
// ~33 GB/s/CU (the practical per-CU ceiling; m97's tuned GEMM sustains ~50). Occupancy/ILP/TLP
// changes never touched this -> dur never moved. Fix: A-REUSE. Each A-fragment now feeds TWO
// row-groups (8 MFMAs per 4 loads, two independent acc chains); 512 blocks halve total A-reads
// -> 8 MB/CU. Phase 3 loops g3=0,1 (same total work). Loss path stays atomic-free (round 7).
__global__ __launch_bounds__(256)
void rvq_main(const float* __restrict__ cb, const float* __restrict__ xT,
              const ushort* __restrict__ cb16, const float* __restrict__ cnorm,
              float* __restrict__ out, double* __restrict__ lossbuf) {
  __shared__ __align__(16) uint4  res16[2048];      // 32 KB fp16 residual, B-frag layout, 2 groups
  __shared__ float candm[64][12];                   // packed score|code, 3 KB
  __shared__ double lred[4];                        // per-wave loss partials

  const int tid = threadIdx.x;
  const int w = tid >> 6, l = tid & 63, n5 = l & 31, h = l >> 5;
  const size_t row0 = (size_t)blockIdx.x * 64;
  const int rowL31 = tid >> 3;          // phase-3 row within group (0..31)
  const int dq = tid & 7;               // phase-3 dim-octant (32 dims)

  float res[2][4][8];                   // f32 residual, both row-groups, register-resident

  // ---- init: residual = x; write fp16 frag image (both groups) ----
#pragma unroll
  for (int g3 = 0; g3 < 2; ++g3) {
#pragma unroll
    for (int cc = 0; cc < 4; ++cc) {
      const int kb = dq * 4 + cc;
      const float* xp = xT + (row0 + g3 * 32 + rowL31) * D_ + kb * 8;
      const float4 x0 = *(const float4*)xp, x1 = *(const float4*)(xp + 4);
      res[g3][cc][0] = x0.x; res[g3][cc][1] = x0.y; res[g3][cc][2] = x0.z; res[g3][cc][3] = x0.w;
      res[g3][cc][4] = x1.x; res[g3][cc][5] = x1.y; res[g3][cc][6] = x1.z; res[g3][cc][7] = x1.w;
      uint4 pv;
      pv.x = __builtin_bit_cast(uint, __builtin_amdgcn_cvt_pkrtz(x0.x, x0.y));
      pv.y = __builtin_bit_cast(uint, __builtin_amdgcn_cvt_pkrtz(x0.z, x0.w));
      pv.z = __builtin_bit_cast(uint, __builtin_amdgcn_cvt_pkrtz(x1.x, x1.y));
      pv.w = __builtin_bit_cast(uint, __builtin_amdgcn_cvt_pkrtz(x1.z, x1.w));
      res16[g3 * 1024 + kb * 32 + (rowL31 ^ dq)] = pv;   // (kb>>2)&7 == dq
    }
  }
  __syncthreads();

  for (int s = 0; s < NQ_; ++s) {
    // ===== K-loop: 8 tiles; per chunk 4 A-loads feed 8 MFMAs (2 row-groups) =====
    float a1v = 3e38f, a2v = 3e38f, a3v = 3e38f;   // g0 chain A (even rr)
    float b1v = 3e38f, b2v = 3e38f, b3v = 3e38f;   // g0 chain B (odd rr)
    float c1v = 3e38f, c2v = 3e38f, c3v = 3e38f;   // g1 chain A
    float d1v = 3e38f, d2v = 3e38f, d3v = 3e38f;   // g1 chain B
    for (int tt = 0; tt < 8; ++tt) {
      const int t = w * 8 + tt;
      const uint4* ap = (const uint4*)(cb16 + ((size_t)(s * 32 + t) * 16) * 512) + l;
      int zr = 0;
      asm volatile("" : "+v"(zr));               // opaque 0: B addresses not loop-invariant
      const uint4* bp = res16 + zr;
      f32x16 acc0, acc1;
#pragma unroll
      for (int r = 0; r < 16; ++r) { acc0[r] = 0.0f; acc1[r] = 0.0f; }
#pragma unroll
      for (int q = 0; q < 4; ++q) {              // 4-chunks bound transient reg pressure
        uint4 av[4], b0[4], b1[4];
#pragma unroll
        for (int c = 0; c < 4; ++c) {
          const int ks = q * 4 + c;
          const int bo = (ks * 2 + h) * 32 + (n5 ^ ((ks >> 1) & 7));
          av[c] = ap[(size_t)ks * 64];
          b0[c] = bp[bo];
          b1[c] = bp[1024 + bo];
        }
#pragma unroll
        for (int c = 0; c < 4; ++c) {
          acc0 = __builtin_amdgcn_mfma_f32_32x32x16_f16(
              __builtin_bit_cast(half8, av[c]), __builtin_bit_cast(half8, b0[c]), acc0, 0, 0, 0);
          acc1 = __builtin_amdgcn_mfma_f32_32x32x16_f16(
              __builtin_bit_cast(half8, av[c]), __builtin_bit_cast(half8, b1[c]), acc1, 0, 0, 0);
        }
      }
      const float* cnb = cnorm + s * K_ + t * 32 + h * 4;
      const uint cbase = (uint)(t * 32 + 4 * h);
#pragma unroll
      for (int qq = 0; qq < 4; ++qq) {                   // cnorm shared by both groups
        const float4 cq = *(const float4*)(cnb + qq * 8);
        const float cna[4] = {cq.x, cq.y, cq.z, cq.w};
#pragma unroll
        for (int rr = 0; rr < 4; ++rr) {
          const int r = qq * 4 + rr;
          const uint code = cbase + (uint)(8 * qq + rr); // == t*32 + (r&3) + 8*(r>>2) + 4*h
          const float f0 = packsc(fmaf(-2.0f, acc0[r], cna[rr]), code);
          const float f1 = packsc(fmaf(-2.0f, acc1[r], cna[rr]), code);
          if (rr & 1) { ins3(b1v, b2v, b3v, f0); ins3(d1v, d2v, d3v, f1); }
          else        { ins3(a1v, a2v, a3v, f0); ins3(c1v, c2v, c3v, f1); }
        }
      }
    }
    // merge chain B into chain A (per group)
    ins3(a1v, a2v, a3v, b1v); ins3(a1v, a2v, a3v, b2v); ins3(a1v, a2v, a3v, b3v);
    ins3(c1v, c2v, c3v, d1v); ins3(c1v, c2v, c3v, d2v); ins3(c1v, c2v, c3v, d3v);
    // merge h-halves (lane l <-> l^32, same x-row, disjoint codes)
    {
      const float o1 = __shfl_xor(a1v, 32), o2 = __shfl_xor(a2v, 32), o3 = __shfl_xor(a3v, 32);
      ins3(a1v, a2v, a3v, o1); ins3(a1v, a2v, a3v, o2); ins3(a1v, a2v, a3v, o3);
      const float p1 = __shfl_xor(c1v, 32), p2 = __shfl_xor(c2v, 32), p3 = __shfl_xor(c3v, 32);
      ins3(c1v, c2v, c3v, p1); ins3(c1v, c2v, c3v, p2); ins3(c1v, c2v, c3v, p3);
    }
    if (h == 0) {
      candm[n5][w * 3 + 0] = a1v; candm[n5][w * 3 + 1] = a2v; candm[n5][w * 3 + 2] = a3v;
      candm[32 + n5][w * 3 + 0] = c1v; candm[32 + n5][w * 3 + 1] = c2v; candm[32 + n5][w * 3 + 2] = c3v;
    }
    __syncthreads();   // all K-loop res16 reads done before phase-3 rewrites

    // ===== phase 3: per thread, both groups; f64 re-eval of top-3-of-12 =====
    double lossW = 0.0;
#pragma unroll
    for (int g3 = 0; g3 < 2; ++g3) {
      const int row = g3 * 32 + rowL31;
      float m1 = 3e38f, m2 = 3e38f, m3 = 3e38f;
#pragma unroll
      for (int cd = 0; cd < 12; ++cd) ins3(m1, m2, m3, candm[row][cd]);
      const int c1 = (int)(__builtin_bit_cast(uint, m1) & 1023u);
      const int c2 = (int)(__builtin_bit_cast(uint, m2) & 1023u);
      const int c3 = (int)(__builtin_bit_cast(uint, m3) & 1023u);

      const float* cbs = cb + (size_t)s * K_ * D_;
      const float* cr0 = cbs + (size_t)c1 * D_;
      const float* cr1 = cbs + (size_t)c2 * D_;
      const float* cr2 = cbs + (size_t)c3 * D_;
      double dd0 = 0.0, dd1 = 0.0, dd2 = 0.0;
#pragma unroll
      for (int cc = 0; cc < 4; ++cc) {
        const int kb = dq * 4 + cc;
        const int go = kb * 8;
        const float4 a0 = *(const float4*)(cr0 + go), a1 = *(const float4*)(cr0 + go + 4);
        const float4 b0 = *(const float4*)(cr1 + go), b1 = *(const float4*)(cr1 + go + 4);
        const float4 g0 = *(const float4*)(cr2 + go), g1 = *(const float4*)(cr2 + go + 4);
        const float af[8] = {a0.x, a0.y, a0.z, a0.w, a1.x, a1.y, a1.z, a1.w};
        const float bf[8] = {b0.x, b0.y, b0.z, b0.w, b1.x, b1.y, b1.z, b1.w};
        const float gf[8] = {g0.x, g0.y, g0.z, g0.w, g1.x, g1.y, g1.z, g1.w};
#pragma unroll
        for (int j = 0; j < 8; ++j) {
          const double r64 = (double)res[g3][cc][j];
          const double u = r64 - (double)af[j]; dd0 += u * u;
          const double v = r64 - (double)bf[j]; dd1 += v * v;
          const double gg = r64 - (double)gf[j]; dd2 += gg * gg;
        }
      }
#pragma unroll
      for (int m = 1; m <= 4; m <<= 1) {
        dd0 += __shfl_xor(dd0, m); dd1 += __shfl_xor(dd1, m); dd2 += __shfl_xor(dd2, m);
      }
      int win = c1; double dwn = dd0;
      if (dd1 < dwn || (dd1 == dwn && c2 < win)) { win = c2; dwn = dd1; }
      if (dd2 < dwn || (dd2 == dwn && c3 < win)) { win = c3; dwn = dd2; }
      const float* crw = cbs + (size_t)win * D_;
#pragma unroll
      for (int cc = 0; cc < 4; ++cc) {
        const int kb = dq * 4 + cc;
        const int go = kb * 8;
        const float4 w0 = *(const float4*)(crw + go), w1 = *(const float4*)(crw + go + 4);
        const float wf[8] = {w0.x, w0.y, w0.z, w0.w, w1.x, w1.y, w1.z, w1.w};
        if (s < NQ_ - 1) {
#pragma unroll
          for (int j = 0; j < 8; ++j) res[g3][cc][j] = res[g3][cc][j] - wf[j]; // f32 = reference
          uint4 pv;
          pv.x = __builtin_bit_cast(uint, __builtin_amdgcn_cvt_pkrtz(res[g3][cc][0], res[g3][cc][1]));
          pv.y = __builtin_bit_cast(uint, __builtin_amdgcn_cvt_pkrtz(res[g3][cc][2], res[g3][cc][3]));
          pv.z = __builtin_bit_cast(uint, __builtin_amdgcn_cvt_pkrtz(res[g3][cc][4], res[g3][cc][5]));
          pv.w = __builtin_bit_cast(uint, __builtin_amdgcn_cvt_pkrtz(res[g3][cc][6], res[g3][cc][7]));
          res16[g3 * 1024 + kb * 32 + (rowL31 ^ dq)] = pv;
        } else {
          const float* xp = xT + (row0 + row) * D_ + go;
          const float4 x0 = *(const float4*)xp, x1 = *(const float4*)(xp + 4);
          const float xf[8] = {x0.x, x0.y, x0.z, x0.w, x1.x, x1.y, x1.z, x1.w};
          float o[8];
#pragma unroll
          for (int j = 0; j < 8; ++j) o[j] = xf[j] - (res[g3][cc][j] - wf[j]);
          float* od = out + (row0 + row) * D_ + go;
          *(float4*)od       = make_float4(o[0], o[1], o[2], o[3]);
          *(float4*)(od + 4) = make_float4(o[4], o[5], o[6], o[7]);
        }
      }
      if (dq == 0) {
        out[IDX_OFF + (size_t)s * (B_ * T_) + row0 + row] = (float)win;
        lossW += dwn;
      }
    }
    // lossW nonzero only on lanes with dq==0 (l % 8 == 0): masks 8/16/32 suffice
#pragma unroll
    for (int m = 8; m <= 32; m <<= 1) lossW += __shfl_xor(lossW, m);
    if (l == 0) lred[w] = lossW;          // per-wave partial -> LDS (no atomics)
    __syncthreads();                      // also fences res16 writes for next stage
    if (tid == 0)                         // one plain store per block per stage, own slot
      lossbuf[(size_t)s * 512 + blockIdx.x] = lred[0] + lred[1] + lred[2] + lred[3];
  }
}

// ---- loss reduce: 8 blocks x 256 thr; block s sums its 512 per-block partials ----
__global__ void rvq_loss(const double* __restrict__ lossbuf, float* __restrict__ out) {
  const int s = blockIdx.x, tid = threadIdx.x;
  double acc = lossbuf[(size_t)s * 512 + tid] + lossbuf[(size_t)s * 512 + tid + 256];
#pragma unroll
  for (int m = 1; m <= 32; m <<= 1) acc += __shfl_xor(acc, m);
  __shared__ double sred[4];
  if ((tid & 63) == 0) sred[tid >> 6] = acc;
  __syncthreads();
  if (tid == 0)
    out[LOSS_OFF + s] =
        (float)(2.0 * (sred[0] + sred[1] + sred[2] + sred[3]) / (double)((size_t)B_ * T_ * D_));
}

extern "C" void kernel_launch(void* const* d_in, const int* in_sizes, int n_in,
                              void* d_out, int out_size, void* d_ws, size_t ws_size,
                              hipStream_t stream) {
  const float* x  = (const float*)d_in[0];   // [B, D, T] f32
  const float* cb = (const float*)d_in[1];   // [NQ, K, D] f32
  float* out = (float*)d_out;
  char* ws = (char*)d_ws;
  float*  xTp   = (float*)(ws + XT_OFF);
  ushort* cb16p = (ushort*)(ws + CB16_OFF);
  float*  cnp   = (float*)(ws + CN_OFF);
  double* lbp   = (double*)(ws + LB_OFF);

  prep_xT<<<2048, 256, 0, stream>>>(x, xTp);
  prep_cb16<<<2048, 256, 0, stream>>>(cb, cb16p, cnp);
  rvq_main<<<512, 256, 0, stream>>>(cb, xTp, cb16p, cnp, out, lbp);
  rvq_loss<<<8, 256, 0, stream>>>(lbp, out);
}